// Round 4
// baseline (2149.765 us; speedup 1.0000x reference)
//
#include <hip/hip_runtime.h>

#define B_   1024
#define TE   168
#define TD   24
#define F_   64
#define H_   128
#define H2_  256
#define G_   512

// ---- workspace float offsets ----
#define OFF_WhT    0          // dec Wh PACKED tiles: 8jt x 8ks x 64lane x 8 halfs (32768 halfs)
#define OFF_dWihT  16384      // dec [dWih|dWhh] PACKED tiles: 32nt x 8ks x 64 x 8 (131072 halfs, spans old dWihT+dWhhT)
#define OFF_ENCB   81920
#define OFF_MIDB   82432
#define OFF_DECB   82944
#define OFF_W16    83456      // fp16 row-major weight block (half offsets below)
#define W16_We     0          // [128][256]
#define W16_Wi     32768      // [128][64]
#define W16_Vd     40960      // [64][128]
#define W16_eWih   49152      // [512][64]
#define W16_eWhh   81920      // [512][128]
#define W16_mWih   147456     // [512][128]
#define W16_mWhh   212992     // [512][128]
#define W16_Wx     278528     // [128][128]
#define W16_TOT    294912     // halfs
#define OFF_MID    230912                         // half [1024][168][128]: h_enc, overwritten in-place by midH
#define OFF_WX     (OFF_MID + (B_*TE*H_)/2)       // half [1024][168][128]
#define OFF_STH    (OFF_WX  + (B_*TE*H_)/2)
#define OFF_STC    (OFF_STH + B_*H_)
#define WS_FLOATS  (OFF_STC + B_*H_)

typedef _Float16 h2 __attribute__((ext_vector_type(2)));
typedef _Float16 f16x8 __attribute__((ext_vector_type(8)));
typedef float    f32x4 __attribute__((ext_vector_type(4)));

__device__ __forceinline__ float fexp2(float x) { return __builtin_amdgcn_exp2f(x); }
__device__ __forceinline__ float frcp(float x)  { return __builtin_amdgcn_rcpf(x); }
#define LOG2E 1.4426950408889634f

__device__ __forceinline__ float sigm(float x) {
    return frcp(1.f + fexp2(-LOG2E * x));
}
__device__ __forceinline__ float tanh_fast(float x) {
    float e = fexp2(2.f * LOG2E * x);
    return 1.f - 2.f * frcp(e + 1.f);
}

__device__ __forceinline__ f32x4 mfma16(f16x8 a, f16x8 b, f32x4 c) {
    return __builtin_amdgcn_mfma_f32_16x16x32_f16(a, b, c, 0, 0, 0);
}

// ---------------- prep: packed dec tiles + fp16 copies + summed biases ----------------
struct PrepArgs {
    const float *We, *Wi, *Vd, *eWih, *eWhh, *eBih, *eBhh,
                *mWih, *mWhh, *mBih, *mBhh, *Wx, *Wh, *dWih, *dWhh, *dBih, *dBhh;
};

__global__ void prep_kernel(PrepArgs a, float* __restrict__ ws) {
    int sec  = blockIdx.x >> 2;
    int base = (blockIdx.x & 3) * blockDim.x + threadIdx.x;
    const int stride = blockDim.x * 4;
    _Float16* w16 = (_Float16*)(ws + OFF_W16);

    if (sec == 0) {
        // Wh packed: dst[((jt*8+ks)*64+lane)*8+e] = Wh[jt*16+cc][ks*32+g*8+e]
        _Float16* hd = (_Float16*)(ws + OFF_WhT);
        for (int o = base; o < 32768; o += stride) {
            int e = o & 7, lane = (o >> 3) & 63, ks = (o >> 9) & 7, jt = o >> 12;
            int cc = lane & 15, g = lane >> 4;
            hd[o] = (_Float16)a.Wh[(jt * 16 + cc) * 256 + ks * 32 + g * 8 + e];
        }
    } else if (sec == 1 || sec == 2) {
        // [dWih|dWhh] packed over K=256: dst[((nt*8+ks)*64+lane)*8+e]
        _Float16* hd = (_Float16*)(ws + OFF_dWihT);
        int o0 = (sec == 2) ? 65536 : 0;
        for (int oo = base; oo < 65536; oo += stride) {
            int o = o0 + oo;
            int e = o & 7, lane = (o >> 3) & 63, ks = (o >> 9) & 7, nt = o >> 12;
            int cc = lane & 15, g = lane >> 4;
            int row = nt * 16 + cc;
            int kcol = ks * 32 + g * 8 + e;
            float v = (kcol < 128) ? a.dWih[row * 128 + kcol] : a.dWhh[row * 128 + (kcol - 128)];
            hd[o] = (_Float16)v;
        }
    } else if (sec == 3) {
        for (int i = base; i < 512; i += stride) ws[OFF_ENCB + i] = a.eBih[i] + a.eBhh[i];
    } else if (sec == 4) {
        for (int i = base; i < 512; i += stride) ws[OFF_MIDB + i] = a.mBih[i] + a.mBhh[i];
    } else if (sec == 5) {
        for (int i = base; i < 512; i += stride) ws[OFF_DECB + i] = a.dBih[i] + a.dBhh[i];
    } else if (sec <= 13) {
        const int dsto[8] = {W16_We, W16_Wi, W16_Vd, W16_eWih, W16_eWhh, W16_mWih, W16_mWhh, W16_Wx};
        const int cnt[8]  = {32768, 8192, 8192, 32768, 65536, 65536, 65536, 16384};
        const float* srcs[8] = {a.We, a.Wi, a.Vd, a.eWih, a.eWhh, a.mWih, a.mWhh, a.Wx};
        int k = sec - 6;
        const float* s = srcs[k];
        _Float16* d = w16 + dsto[k];
        int n = cnt[k];
        for (int i = base; i < n; i += stride) d[i] = (_Float16)s[i];
    }
}

// ---------------- encoder: 64 blocks x 512 thr, 16 rows/block (unchanged) ----------------
__global__ __launch_bounds__(512, 1) void enc_kernel(
    const float* __restrict__ x_all,
    const float* __restrict__ Wi_b,
    const float* __restrict__ Vd_b,
    float* __restrict__ ws)
{
    __shared__ __align__(16) _Float16 m1In[16][328];   // [h(0:128)|c(128:256)|x(256:320)]
    __shared__ __align__(16) _Float16 encIn[16][200];  // [xin(0:64)|h_enc(64:192)]
    __shared__ __align__(16) _Float16 avT[16][136];    // tanh(m1) (K=128)
    __shared__ __align__(16) float sS[16][68];         // raw attention scores
    __shared__ __align__(16) float xf[16][64];         // current x fp32
    __shared__ __align__(16) float cE[16][132];        // enc c fp32 master
    __shared__ float bWi[H_], bVd[F_], bE[G_];

    const int tid  = threadIdx.x;
    const int wave = tid >> 6;
    const int lane = tid & 63;
    const int g    = lane >> 4;   // k-group (A/B frag) / row-quad (C frag)
    const int cc   = lane & 15;   // A row / B col / C col
    const int b0   = blockIdx.x * 16;
    const int col  = wave * 16 + cc;

    for (int i = tid; i < 16 * 328; i += 512) ((_Float16*)m1In)[i]  = (_Float16)0.f;
    for (int i = tid; i < 16 * 200; i += 512) ((_Float16*)encIn)[i] = (_Float16)0.f;
    for (int i = tid; i < 16 * 132; i += 512) ((float*)cE)[i] = 0.f;
    if (tid < H_) bWi[tid] = Wi_b[tid];
    if (tid < F_) bVd[tid] = Vd_b[tid];
    bE[tid] = ws[OFF_ENCB + tid];
    if (tid < 256) {  // x for t=0
        int m = tid >> 4, c4 = (tid & 15) * 4;
        float4 v = *(const float4*)&x_all[((size_t)(b0 + m) * TE + 0) * F_ + c4];
        *(float4*)&xf[m][c4] = v;
        m1In[m][256 + c4]     = (_Float16)v.x;
        m1In[m][256 + c4 + 1] = (_Float16)v.y;
        m1In[m][256 + c4 + 2] = (_Float16)v.z;
        m1In[m][256 + c4 + 3] = (_Float16)v.w;
    }

    // ---- persistent per-wave B-fragments (fixed across all t) ----
    const _Float16* w16 = (const _Float16*)(ws + OFF_W16);
    f16x8 wWe[8], wWi[2], wVd[4], wIh[4][2], wHh[4][4];
    {
        const _Float16* p = w16 + W16_We + (size_t)col * 256 + 8 * g;
        #pragma unroll
        for (int ks = 0; ks < 8; ++ks) wWe[ks] = *(const f16x8*)(p + ks * 32);
        const _Float16* p2 = w16 + W16_Wi + (size_t)col * 64 + 8 * g;
        wWi[0] = *(const f16x8*)(p2);
        wWi[1] = *(const f16x8*)(p2 + 32);
        if (wave < 4) {
            const _Float16* p3 = w16 + W16_Vd + (size_t)col * 128 + 8 * g;
            #pragma unroll
            for (int ks = 0; ks < 4; ++ks) wVd[ks] = *(const f16x8*)(p3 + ks * 32);
        } else {
            #pragma unroll
            for (int ks = 0; ks < 4; ++ks) wVd[ks] = f16x8{};
        }
        #pragma unroll
        for (int q = 0; q < 4; ++q) {
            const _Float16* pi = w16 + W16_eWih + (size_t)(q * 128 + col) * 64 + 8 * g;
            wIh[q][0] = *(const f16x8*)(pi);
            wIh[q][1] = *(const f16x8*)(pi + 32);
            const _Float16* ph = w16 + W16_eWhh + (size_t)(q * 128 + col) * 128 + 8 * g;
            #pragma unroll
            for (int ks = 0; ks < 4; ++ks) wHh[q][ks] = *(const f16x8*)(ph + ks * 32);
        }
    }
    _Float16* hencG = (_Float16*)(ws + OFF_MID);
    __syncthreads();

    float4 xr = make_float4(0.f, 0.f, 0.f, 0.f);  // x_{t+1} prefetch (waves 4-7)

    for (int t = 0; t < TE; ++t) {
        // ---- P1: m1 = [h|c|x] @ [We|Wi]^T  -> av = tanh(m1 + bWi)
        {
            f16x8 aF[10];
            #pragma unroll
            for (int ks = 0; ks < 10; ++ks)
                aF[ks] = *(const f16x8*)&m1In[cc][ks * 32 + 8 * g];
            f32x4 acc = {0.f, 0.f, 0.f, 0.f};
            #pragma unroll
            for (int ks = 0; ks < 8; ++ks)
                acc = mfma16(aF[ks], wWe[ks], acc);
            acc = mfma16(aF[8], wWi[0], acc);
            acc = mfma16(aF[9], wWi[1], acc);
            float bw = bWi[col];
            #pragma unroll
            for (int r = 0; r < 4; ++r)
                avT[4 * g + r][col] = (_Float16)tanh_fast(acc[r] + bw);
        }
        __syncthreads();

        // ---- P2: s = av @ Vd^T (waves 0-3, K=128); waves 4-7 prefetch x_{t+1}
        if (wave < 4) {
            f16x8 aF[4];
            #pragma unroll
            for (int ks = 0; ks < 4; ++ks)
                aF[ks] = *(const f16x8*)&avT[cc][ks * 32 + 8 * g];
            f32x4 acc = {0.f, 0.f, 0.f, 0.f};
            #pragma unroll
            for (int ks = 0; ks < 4; ++ks)
                acc = mfma16(aF[ks], wVd[ks], acc);
            float bv = bVd[col];
            #pragma unroll
            for (int r = 0; r < 4; ++r)
                sS[4 * g + r][col] = acc[r] + bv;
        } else if (t + 1 < TE) {
            int q = tid - 256, m = q >> 4, c4 = (q & 15) * 4;
            xr = *(const float4*)&x_all[((size_t)(b0 + m) * TE + (t + 1)) * F_ + c4];
        }
        __syncthreads();

        // ---- P2b: softmax over 64 + xin = x * softmax(s). row = half-wave
        {
            int m = tid >> 5, c = tid & 31;
            float v0 = sS[m][c], v1 = sS[m][c + 32];
            float mx = fmaxf(v0, v1);
            #pragma unroll
            for (int off = 16; off > 0; off >>= 1) mx = fmaxf(mx, __shfl_xor(mx, off, 64));
            float e0 = fexp2((v0 - mx) * LOG2E);
            float e1 = fexp2((v1 - mx) * LOG2E);
            float sm = e0 + e1;
            #pragma unroll
            for (int off = 16; off > 0; off >>= 1) sm += __shfl_xor(sm, off, 64);
            float rs = frcp(sm);
            encIn[m][c]      = (_Float16)(xf[m][c]      * e0 * rs);
            encIn[m][c + 32] = (_Float16)(xf[m][c + 32] * e1 * rs);
        }
        __syncthreads();

        // ---- P4: enc gates = [xin|h] @ [eWih|eWhh]^T  (K=192; 4 gate-tiles per wave)
        f32x4 ge[4];
        {
            f16x8 aF[6];
            #pragma unroll
            for (int ks = 0; ks < 6; ++ks)
                aF[ks] = *(const f16x8*)&encIn[cc][ks * 32 + 8 * g];
            #pragma unroll
            for (int q = 0; q < 4; ++q) {
                f32x4 acc = {0.f, 0.f, 0.f, 0.f};
                acc = mfma16(aF[0], wIh[q][0], acc);
                acc = mfma16(aF[1], wIh[q][1], acc);
                #pragma unroll
                for (int ks = 0; ks < 4; ++ks)
                    acc = mfma16(aF[2 + ks], wHh[q][ks], acc);
                ge[q] = acc;
            }
        }
        __syncthreads();   // all encIn reads done
        // ---- ep: enc LSTM cell (in-register gates) + h_enc global store + x install
        {
            float bi = bE[col], bf = bE[col + 128], bg = bE[col + 256], bo = bE[col + 384];
            #pragma unroll
            for (int r = 0; r < 4; ++r) {
                int m = 4 * g + r;
                float gi = ge[0][r] + bi, gf = ge[1][r] + bf,
                      gg = ge[2][r] + bg, go = ge[3][r] + bo;
                float cn = sigm(gf) * cE[m][col] + sigm(gi) * tanh_fast(gg);
                float h  = sigm(go) * tanh_fast(cn);
                cE[m][col] = cn;
                _Float16 hh = (_Float16)h;
                encIn[m][64 + col] = hh;
                m1In[m][col]       = hh;
                m1In[m][128 + col] = (_Float16)cn;
                hencG[((size_t)(b0 + m) * TE + t) * H_ + col] = hh;
            }
            if (tid >= 256 && t + 1 < TE) {
                int q = tid - 256, m = q >> 4, c4 = (q & 15) * 4;
                *(float4*)&xf[m][c4] = xr;
                m1In[m][256 + c4]     = (_Float16)xr.x;
                m1In[m][256 + c4 + 1] = (_Float16)xr.y;
                m1In[m][256 + c4 + 2] = (_Float16)xr.z;
                m1In[m][256 + c4 + 3] = (_Float16)xr.w;
            }
        }
        __syncthreads();
    }
}

// ---------------- mid LSTM: 64 blocks x 512 thr, 16 rows/block (unchanged) ----------------
__global__ __launch_bounds__(512, 1) void mid_kernel(
    const float* __restrict__ Wx_b,
    float* __restrict__ ws)
{
    __shared__ __align__(16) _Float16 midIn[16][264];  // [h_enc(0:128)|h_mid(128:256)]
    __shared__ __align__(16) float cM[16][132];        // mid c fp32 master
    __shared__ float bM[G_], bWx[H_];

    const int tid  = threadIdx.x;
    const int wave = tid >> 6;
    const int lane = tid & 63;
    const int g    = lane >> 4;
    const int cc   = lane & 15;
    const int b0   = blockIdx.x * 16;
    const int col  = wave * 16 + cc;

    for (int i = tid; i < 16 * 264; i += 512) ((_Float16*)midIn)[i] = (_Float16)0.f;
    for (int i = tid; i < 16 * 132; i += 512) ((float*)cM)[i] = 0.f;
    if (tid < H_) bWx[tid] = Wx_b[tid];
    bM[tid] = ws[OFF_MIDB + tid];

    // ---- persistent per-wave B-fragments ----
    const _Float16* w16 = (const _Float16*)(ws + OFF_W16);
    f16x8 wIhB[4][4], wHhB[4][4], wWx[4];
    {
        #pragma unroll
        for (int q = 0; q < 4; ++q) {
            const _Float16* pi = w16 + W16_mWih + (size_t)(q * 128 + col) * 128 + 8 * g;
            const _Float16* ph = w16 + W16_mWhh + (size_t)(q * 128 + col) * 128 + 8 * g;
            #pragma unroll
            for (int ks = 0; ks < 4; ++ks) {
                wIhB[q][ks] = *(const f16x8*)(pi + ks * 32);
                wHhB[q][ks] = *(const f16x8*)(ph + ks * 32);
            }
        }
        const _Float16* px = w16 + W16_Wx + (size_t)col * 128 + 8 * g;
        #pragma unroll
        for (int ks = 0; ks < 4; ++ks) wWx[ks] = *(const f16x8*)(px + ks * 32);
    }

    _Float16* hencG = (_Float16*)(ws + OFF_MID);   // h_enc in, midH out (in-place)
    _Float16* wxH   = (_Float16*)(ws + OFF_WX);
    __syncthreads();

    // install h_enc(0)
    if (tid < 256) {
        int m = tid >> 4, s8 = (tid & 15) * 8;
        *(f16x8*)&midIn[m][s8] = *(const f16x8*)&hencG[((size_t)(b0 + m) * TE + 0) * H_ + s8];
    }
    __syncthreads();

    f16x8 hpre = {};
    f32x4 accx = {0.f, 0.f, 0.f, 0.f};

    for (int t = 0; t < TE; ++t) {
        // ---- P6: mid gates = [h_enc(t)|h_mid(t-1)] @ [mWih|mWhh]^T (K=256) + wx(t-1)
        f32x4 gm[4];
        {
            f16x8 aF[8];
            #pragma unroll
            for (int ks = 0; ks < 8; ++ks)
                aF[ks] = *(const f16x8*)&midIn[cc][ks * 32 + 8 * g];
            #pragma unroll
            for (int q = 0; q < 4; ++q) {
                f32x4 acc = {0.f, 0.f, 0.f, 0.f};
                #pragma unroll
                for (int ks = 0; ks < 4; ++ks)
                    acc = mfma16(aF[ks], wIhB[q][ks], acc);
                #pragma unroll
                for (int ks = 0; ks < 4; ++ks)
                    acc = mfma16(aF[4 + ks], wHhB[q][ks], acc);
                gm[q] = acc;
            }
            if (t > 0) {   // wx(t-1) = h_mid(t-1) @ Wx^T (aF[4..7] already hold h_mid(t-1))
                f32x4 acc = {0.f, 0.f, 0.f, 0.f};
                #pragma unroll
                for (int ks = 0; ks < 4; ++ks)
                    acc = mfma16(aF[4 + ks], wWx[ks], acc);
                accx = acc;
            }
        }
        if (tid < 256 && t + 1 < TE) {   // prefetch h_enc(t+1)
            int m = tid >> 4, s8 = (tid & 15) * 8;
            hpre = *(const f16x8*)&hencG[((size_t)(b0 + m) * TE + (t + 1)) * H_ + s8];
        }
        __syncthreads();

        // ---- ep: mid LSTM cell + midH store (in-place) + wx(t-1) store + h_enc(t+1) install
        {
            float bi = bM[col], bf = bM[col + 128], bg = bM[col + 256], bo = bM[col + 384];
            float bw = bWx[col];
            #pragma unroll
            for (int r = 0; r < 4; ++r) {
                int m = 4 * g + r;
                float gi = gm[0][r] + bi, gf = gm[1][r] + bf,
                      gg = gm[2][r] + bg, go = gm[3][r] + bo;
                float cn = sigm(gf) * cM[m][col] + sigm(gi) * tanh_fast(gg);
                float h  = sigm(go) * tanh_fast(cn);
                cM[m][col] = cn;
                _Float16 hh = (_Float16)h;
                midIn[m][128 + col] = hh;
                hencG[((size_t)(b0 + m) * TE + t) * H_ + col] = hh;   // midH(t)
                if (t > 0)
                    wxH[((size_t)(b0 + m) * TE + (t - 1)) * H_ + col] = (_Float16)(accx[r] + bw);
            }
            if (tid < 256 && t + 1 < TE) {
                int m = tid >> 4, s8 = (tid & 15) * 8;
                *(f16x8*)&midIn[m][s8] = hpre;
            }
        }
        __syncthreads();
    }

    // final wx(TE-1)
    {
        f16x8 ax[4];
        #pragma unroll
        for (int ks = 0; ks < 4; ++ks)
            ax[ks] = *(const f16x8*)&midIn[cc][128 + ks * 32 + 8 * g];
        f32x4 acc = {0.f, 0.f, 0.f, 0.f};
        #pragma unroll
        for (int ks = 0; ks < 4; ++ks)
            acc = mfma16(ax[ks], wWx[ks], acc);
        float bw = bWx[col];
        #pragma unroll
        for (int r = 0; r < 4; ++r) {
            int m = 4 * g + r;
            wxH[((size_t)(b0 + m) * TE + (TE - 1)) * H_ + col] = (_Float16)(acc[r] + bw);
        }
    }
    // final states for decoder
    for (int idx = tid; idx < 2048; idx += 512) {
        int m = idx >> 7, j = idx & 127;
        ws[OFF_STH + (b0 + m) * H_ + j] = (float)midIn[m][128 + j];
        ws[OFF_STC + (b0 + m) * H_ + j] = cM[m][j];
    }
}

// ---------------- decoder v3: 256 blocks x 512 thr, 4 rows/block, MFMA + NT streaming ----------------
__global__ __launch_bounds__(512, 2) void dec_kernel(
    const float* __restrict__ Vw_in,
    const float* __restrict__ Vb_in,
    const float* __restrict__ rw_in,
    const float* __restrict__ rb_in,
    const float* __restrict__ ws,
    float* __restrict__ out)
{
    __shared__ __align__(16) _Float16 hcA[16][264];    // A for P1: [h|c] rows 0-3, rows 4-15 zero
    __shared__ __align__(16) _Float16 dinA[16][264];   // A for P4: [din|h] rows 0-3, rows 4-15 zero
    __shared__ __align__(16) float qv[4][132];         // q fp32
    __shared__ __align__(16) float sv[4][TE];          // scores
    __shared__ __align__(16) float dpart[8][4][132];   // P3 partials
    __shared__ __align__(16) float ggs[4][G_];         // gates
    __shared__ __align__(16) float cD[4][H_];          // c fp32 master
    __shared__ __align__(16) float hFl[4][H_];         // h fp32 (output dot)
    __shared__ float bDL[G_], VwL[H_], rwL[H_];

    const int tid  = threadIdx.x;
    const int wave = tid >> 6;
    const int lane = tid & 63;
    const int g    = lane >> 4;
    const int cc   = lane & 15;
    const int b0   = blockIdx.x * 4;
    const float Vb = Vb_in[0], rb = rb_in[0];

    // zero A-pads, then fill rows 0-3
    for (int i = tid; i < 16 * 264; i += 512) {
        ((_Float16*)hcA)[i]  = (_Float16)0.f;
        ((_Float16*)dinA)[i] = (_Float16)0.f;
    }
    bDL[tid] = ws[OFF_DECB + tid];
    if (tid < H_) { VwL[tid] = Vw_in[tid]; rwL[tid] = rw_in[tid]; }
    __syncthreads();
    {
        int r = tid >> 7, j = tid & 127;
        float sh = ws[OFF_STH + (size_t)(b0 + r) * H_ + j];
        float sc = ws[OFF_STC + (size_t)(b0 + r) * H_ + j];
        hcA[r][j]        = (_Float16)sh;
        hcA[r][128 + j]  = (_Float16)sc;
        dinA[r][128 + j] = (_Float16)sh;
        cD[r][j] = sc;
    }
    __syncthreads();

    const _Float16* WhP  = (const _Float16*)(ws + OFF_WhT);
    const _Float16* dWP  = (const _Float16*)(ws + OFF_dWihT);
    const _Float16* wxG  = (const _Float16*)(ws + OFF_WX);
    const _Float16* midG = (const _Float16*)(ws + OFF_MID);

    for (int td = 0; td < TD; ++td) {
        // ---- P1: q[4][128] = [h|c] @ Wh^T via MFMA (M=4). wave = 16-col tile, K=256
        {
            f16x8 aF[8];
            #pragma unroll
            for (int ks = 0; ks < 8; ++ks)
                aF[ks] = *(const f16x8*)&hcA[cc][ks * 32 + 8 * g];
            f32x4 acc = {0.f, 0.f, 0.f, 0.f};
            #pragma unroll
            for (int ks = 0; ks < 8; ++ks) {
                f16x8 wb = *(const f16x8*)(WhP + (((size_t)(wave * 8 + ks) * 64 + lane) * 8));
                acc = mfma16(aF[ks], wb, acc);
            }
            if (g == 0) {
                #pragma unroll
                for (int r = 0; r < 4; ++r) qv[r][wave * 16 + cc] = acc[r];
            }
        }
        __syncthreads();

        // ---- P2: scores. task = (r, tp): full 128-wide tanh dot per thread, NT wx loads
        for (int task = tid; task < 4 * TE; task += 512) {
            int r  = (task >= 2 * TE) ? ((task >= 3 * TE) ? 3 : 2) : ((task >= TE) ? 1 : 0);
            int tp = task - r * TE;
            const _Float16* wxp = wxG + ((size_t)(b0 + r) * TE + tp) * H_;
            float acc = Vb;
            #pragma unroll 4
            for (int k8 = 0; k8 < 16; ++k8) {
                f16x8 wv = __builtin_nontemporal_load((const f16x8*)(wxp + k8 * 8));
                int j = k8 * 8;
                float4 q0 = *(const float4*)&qv[r][j], q1 = *(const float4*)&qv[r][j + 4];
                float4 v0 = *(const float4*)&VwL[j],   v1 = *(const float4*)&VwL[j + 4];
                acc += tanh_fast(q0.x + (float)wv[0]) * v0.x + tanh_fast(q0.y + (float)wv[1]) * v0.y
                     + tanh_fast(q0.z + (float)wv[2]) * v0.z + tanh_fast(q0.w + (float)wv[3]) * v0.w;
                acc += tanh_fast(q1.x + (float)wv[4]) * v1.x + tanh_fast(q1.y + (float)wv[5]) * v1.y
                     + tanh_fast(q1.z + (float)wv[6]) * v1.z + tanh_fast(q1.w + (float)wv[7]) * v1.w;
            }
            sv[r][tp] = acc;
        }
        __syncthreads();

        // ---- P3: dec_in partials. tid = sl*64 + r*16 + j8; 21 tp each, NT mid loads
        {
            int sl = tid >> 6, rem = tid & 63, r = rem >> 4, j8 = rem & 15;
            int t0 = sl * 21;
            const _Float16* mp = midG + (size_t)(b0 + r) * TE * H_ + j8 * 8;
            float a0 = 0.f, a1 = 0.f, a2 = 0.f, a3 = 0.f, a4 = 0.f, a5 = 0.f, a6 = 0.f, a7 = 0.f;
            for (int tp = t0; tp < t0 + 21; ++tp) {
                float s = sv[r][tp];
                f16x8 mv = __builtin_nontemporal_load((const f16x8*)(mp + (size_t)tp * H_));
                a0 = __builtin_fmaf(s, (float)mv[0], a0);
                a1 = __builtin_fmaf(s, (float)mv[1], a1);
                a2 = __builtin_fmaf(s, (float)mv[2], a2);
                a3 = __builtin_fmaf(s, (float)mv[3], a3);
                a4 = __builtin_fmaf(s, (float)mv[4], a4);
                a5 = __builtin_fmaf(s, (float)mv[5], a5);
                a6 = __builtin_fmaf(s, (float)mv[6], a6);
                a7 = __builtin_fmaf(s, (float)mv[7], a7);
            }
            float* dp = &dpart[sl][r][j8 * 8];
            dp[0] = a0; dp[1] = a1; dp[2] = a2; dp[3] = a3;
            dp[4] = a4; dp[5] = a5; dp[6] = a6; dp[7] = a7;
        }
        __syncthreads();
        // ---- P3b: combine 8 -> dinA fp16
        {
            int r = tid >> 7, j = tid & 127;
            float d = ((dpart[0][r][j] + dpart[1][r][j]) + (dpart[2][r][j] + dpart[3][r][j]))
                    + ((dpart[4][r][j] + dpart[5][r][j]) + (dpart[6][r][j] + dpart[7][r][j]));
            dinA[r][j] = (_Float16)d;
        }
        __syncthreads();

        // ---- P4: gates[4][512] = [din|h] @ [dWih|dWhh]^T via MFMA (M=4). 4 n-tiles/wave, K=256
        {
            f16x8 aF[8];
            #pragma unroll
            for (int ks = 0; ks < 8; ++ks)
                aF[ks] = *(const f16x8*)&dinA[cc][ks * 32 + 8 * g];
            #pragma unroll
            for (int q = 0; q < 4; ++q) {
                int nt = wave * 4 + q;
                f32x4 acc = {0.f, 0.f, 0.f, 0.f};
                #pragma unroll
                for (int ks = 0; ks < 8; ++ks) {
                    f16x8 wb = *(const f16x8*)(dWP + (((size_t)(nt * 8 + ks) * 64 + lane) * 8));
                    acc = mfma16(aF[ks], wb, acc);
                }
                if (g == 0) {
                    #pragma unroll
                    for (int r = 0; r < 4; ++r) ggs[r][nt * 16 + cc] = acc[r];
                }
            }
        }
        __syncthreads();

        // ---- P5: LSTM cell
        {
            int r = tid >> 7, j = tid & 127;
            float gi = ggs[r][j]       + bDL[j];
            float gf = ggs[r][j + 128] + bDL[j + 128];
            float gg = ggs[r][j + 256] + bDL[j + 256];
            float go = ggs[r][j + 384] + bDL[j + 384];
            float cn = sigm(gf) * cD[r][j] + sigm(gi) * tanh_fast(gg);
            float h  = sigm(go) * tanh_fast(cn);
            cD[r][j]  = cn;
            hFl[r][j] = h;
            hcA[r][j]        = (_Float16)h;
            hcA[r][128 + j]  = (_Float16)cn;
            dinA[r][128 + j] = (_Float16)h;
        }
        __syncthreads();

        // ---- P6: output dot (waves 0-3; hFl stable until next P5)
        if (wave < 4) {
            float v = hFl[wave][lane] * rwL[lane] + hFl[wave][lane + 64] * rwL[lane + 64];
            #pragma unroll
            for (int off = 32; off > 0; off >>= 1) v += __shfl_xor(v, off, 64);
            if (lane == 0) out[(size_t)(b0 + wave) * TD + td] = v + rb;
        }
    }
}

extern "C" void kernel_launch(void* const* d_in, const int* in_sizes, int n_in,
                              void* d_out, int out_size, void* d_ws, size_t ws_size,
                              hipStream_t stream)
{
    (void)in_sizes; (void)n_in; (void)out_size;
    if (ws_size < (size_t)WS_FLOATS * sizeof(float)) return;

    const float* x_all = (const float*)d_in[0];
    const float* Wi_b  = (const float*)d_in[3];
    const float* Vd_b  = (const float*)d_in[6];
    const float* Wx_b  = (const float*)d_in[16];
    const float* V_w   = (const float*)d_in[18];
    const float* V_b   = (const float*)d_in[19];
    const float* reg_w = (const float*)d_in[24];
    const float* reg_b = (const float*)d_in[25];
    float* ws  = (float*)d_ws;
    float* out = (float*)d_out;

    PrepArgs pa{
        (const float*)d_in[4],  // We_w
        (const float*)d_in[2],  // Wi_w
        (const float*)d_in[5],  // Vd_w
        (const float*)d_in[7],  // enc_Wih
        (const float*)d_in[8],  // enc_Whh
        (const float*)d_in[9],  // enc_bih
        (const float*)d_in[10], // enc_bhh
        (const float*)d_in[11], // mid_Wih
        (const float*)d_in[12], // mid_Whh
        (const float*)d_in[13], // mid_bih
        (const float*)d_in[14], // mid_bhh
        (const float*)d_in[15], // Wx_w
        (const float*)d_in[17], // Wh_w
        (const float*)d_in[20], // dec_Wih
        (const float*)d_in[21], // dec_Whh
        (const float*)d_in[22], // dec_bih
        (const float*)d_in[23]  // dec_bhh
    };

    prep_kernel<<<56, 256, 0, stream>>>(pa, ws);
    enc_kernel<<<64, 512, 0, stream>>>(x_all, Wi_b, Vd_b, ws);
    mid_kernel<<<64, 512, 0, stream>>>(Wx_b, ws);
    dec_kernel<<<256, 512, 0, stream>>>(V_w, V_b, reg_w, reg_b, ws, out);
}

// Round 5
// 1374.469 us; speedup vs baseline: 1.5641x; 1.5641x over previous
//
#include <hip/hip_runtime.h>

#define B_   1024
#define TE   168
#define TD   24
#define F_   64
#define H_   128
#define H2_  256
#define G_   512

// ---- workspace float offsets ----
#define OFF_WhT    0          // dec Wh PACKED tiles: 8jt x 8ks x 64lane x 8 halfs (32768 halfs)
#define OFF_dWihT  16384      // dec [dWih|dWhh] PACKED tiles: 32nt x 8ks x 64 x 8 (131072 halfs)
#define OFF_ENCB   81920
#define OFF_MIDB   82432
#define OFF_DECB   82944
#define OFF_W16    83456      // fp16 row-major weight block (half offsets below)
#define W16_We     0          // [128][256]
#define W16_Wi     32768      // [128][64]
#define W16_Vd     40960      // [64][128]
#define W16_eWih   49152      // [512][64]
#define W16_eWhh   81920      // [512][128]
#define W16_mWih   147456     // [512][128]
#define W16_mWhh   212992     // [512][128]
#define W16_Wx     278528     // [128][128]
#define W16_TOT    294912     // halfs
#define OFF_MID    230912                         // half [1024][168][128]: h_enc, overwritten in-place by midH
#define OFF_WX     (OFF_MID + (B_*TE*H_)/2)       // half [1024][168][128]
#define OFF_STH    (OFF_WX  + (B_*TE*H_)/2)
#define OFF_STC    (OFF_STH + B_*H_)
#define WS_FLOATS  (OFF_STC + B_*H_)

typedef _Float16 h2 __attribute__((ext_vector_type(2)));
typedef _Float16 f16x8 __attribute__((ext_vector_type(8)));
typedef float    f32x4 __attribute__((ext_vector_type(4)));

__device__ __forceinline__ float fexp2(float x) { return __builtin_amdgcn_exp2f(x); }
__device__ __forceinline__ float frcp(float x)  { return __builtin_amdgcn_rcpf(x); }
#define LOG2E 1.4426950408889634f

__device__ __forceinline__ float sigm(float x) {
    return frcp(1.f + fexp2(-LOG2E * x));
}
__device__ __forceinline__ float tanh_fast(float x) {
    float e = fexp2(2.f * LOG2E * x);
    return 1.f - 2.f * frcp(e + 1.f);
}

__device__ __forceinline__ f32x4 mfma16(f16x8 a, f16x8 b, f32x4 c) {
    return __builtin_amdgcn_mfma_f32_16x16x32_f16(a, b, c, 0, 0, 0);
}

// ---------------- prep: packed dec tiles + fp16 copies + summed biases ----------------
struct PrepArgs {
    const float *We, *Wi, *Vd, *eWih, *eWhh, *eBih, *eBhh,
                *mWih, *mWhh, *mBih, *mBhh, *Wx, *Wh, *dWih, *dWhh, *dBih, *dBhh;
};

__global__ void prep_kernel(PrepArgs a, float* __restrict__ ws) {
    int sec  = blockIdx.x >> 2;
    int base = (blockIdx.x & 3) * blockDim.x + threadIdx.x;
    const int stride = blockDim.x * 4;
    _Float16* w16 = (_Float16*)(ws + OFF_W16);

    if (sec == 0) {
        // Wh packed: dst[((jt*8+ks)*64+lane)*8+e] = Wh[jt*16+cc][ks*32+g*8+e]
        _Float16* hd = (_Float16*)(ws + OFF_WhT);
        for (int o = base; o < 32768; o += stride) {
            int e = o & 7, lane = (o >> 3) & 63, ks = (o >> 9) & 7, jt = o >> 12;
            int cc = lane & 15, g = lane >> 4;
            hd[o] = (_Float16)a.Wh[(jt * 16 + cc) * 256 + ks * 32 + g * 8 + e];
        }
    } else if (sec == 1 || sec == 2) {
        // [dWih|dWhh] packed over K=256: dst[((nt*8+ks)*64+lane)*8+e]
        _Float16* hd = (_Float16*)(ws + OFF_dWihT);
        int o0 = (sec == 2) ? 65536 : 0;
        for (int oo = base; oo < 65536; oo += stride) {
            int o = o0 + oo;
            int e = o & 7, lane = (o >> 3) & 63, ks = (o >> 9) & 7, nt = o >> 12;
            int cc = lane & 15, g = lane >> 4;
            int row = nt * 16 + cc;
            int kcol = ks * 32 + g * 8 + e;
            float v = (kcol < 128) ? a.dWih[row * 128 + kcol] : a.dWhh[row * 128 + (kcol - 128)];
            hd[o] = (_Float16)v;
        }
    } else if (sec == 3) {
        for (int i = base; i < 512; i += stride) ws[OFF_ENCB + i] = a.eBih[i] + a.eBhh[i];
    } else if (sec == 4) {
        for (int i = base; i < 512; i += stride) ws[OFF_MIDB + i] = a.mBih[i] + a.mBhh[i];
    } else if (sec == 5) {
        for (int i = base; i < 512; i += stride) ws[OFF_DECB + i] = a.dBih[i] + a.dBhh[i];
    } else if (sec <= 13) {
        const int dsto[8] = {W16_We, W16_Wi, W16_Vd, W16_eWih, W16_eWhh, W16_mWih, W16_mWhh, W16_Wx};
        const int cnt[8]  = {32768, 8192, 8192, 32768, 65536, 65536, 65536, 16384};
        const float* srcs[8] = {a.We, a.Wi, a.Vd, a.eWih, a.eWhh, a.mWih, a.mWhh, a.Wx};
        int k = sec - 6;
        const float* s = srcs[k];
        _Float16* d = w16 + dsto[k];
        int n = cnt[k];
        for (int i = base; i < n; i += stride) d[i] = (_Float16)s[i];
    }
}

// ---------------- encoder: 64 blocks x 512 thr, 16 rows/block (unchanged) ----------------
__global__ __launch_bounds__(512, 1) void enc_kernel(
    const float* __restrict__ x_all,
    const float* __restrict__ Wi_b,
    const float* __restrict__ Vd_b,
    float* __restrict__ ws)
{
    __shared__ __align__(16) _Float16 m1In[16][328];   // [h(0:128)|c(128:256)|x(256:320)]
    __shared__ __align__(16) _Float16 encIn[16][200];  // [xin(0:64)|h_enc(64:192)]
    __shared__ __align__(16) _Float16 avT[16][136];    // tanh(m1) (K=128)
    __shared__ __align__(16) float sS[16][68];         // raw attention scores
    __shared__ __align__(16) float xf[16][64];         // current x fp32
    __shared__ __align__(16) float cE[16][132];        // enc c fp32 master
    __shared__ float bWi[H_], bVd[F_], bE[G_];

    const int tid  = threadIdx.x;
    const int wave = tid >> 6;
    const int lane = tid & 63;
    const int g    = lane >> 4;   // k-group (A/B frag) / row-quad (C frag)
    const int cc   = lane & 15;   // A row / B col / C col
    const int b0   = blockIdx.x * 16;
    const int col  = wave * 16 + cc;

    for (int i = tid; i < 16 * 328; i += 512) ((_Float16*)m1In)[i]  = (_Float16)0.f;
    for (int i = tid; i < 16 * 200; i += 512) ((_Float16*)encIn)[i] = (_Float16)0.f;
    for (int i = tid; i < 16 * 132; i += 512) ((float*)cE)[i] = 0.f;
    if (tid < H_) bWi[tid] = Wi_b[tid];
    if (tid < F_) bVd[tid] = Vd_b[tid];
    bE[tid] = ws[OFF_ENCB + tid];
    if (tid < 256) {  // x for t=0
        int m = tid >> 4, c4 = (tid & 15) * 4;
        float4 v = *(const float4*)&x_all[((size_t)(b0 + m) * TE + 0) * F_ + c4];
        *(float4*)&xf[m][c4] = v;
        m1In[m][256 + c4]     = (_Float16)v.x;
        m1In[m][256 + c4 + 1] = (_Float16)v.y;
        m1In[m][256 + c4 + 2] = (_Float16)v.z;
        m1In[m][256 + c4 + 3] = (_Float16)v.w;
    }

    // ---- persistent per-wave B-fragments (fixed across all t) ----
    const _Float16* w16 = (const _Float16*)(ws + OFF_W16);
    f16x8 wWe[8], wWi[2], wVd[4], wIh[4][2], wHh[4][4];
    {
        const _Float16* p = w16 + W16_We + (size_t)col * 256 + 8 * g;
        #pragma unroll
        for (int ks = 0; ks < 8; ++ks) wWe[ks] = *(const f16x8*)(p + ks * 32);
        const _Float16* p2 = w16 + W16_Wi + (size_t)col * 64 + 8 * g;
        wWi[0] = *(const f16x8*)(p2);
        wWi[1] = *(const f16x8*)(p2 + 32);
        if (wave < 4) {
            const _Float16* p3 = w16 + W16_Vd + (size_t)col * 128 + 8 * g;
            #pragma unroll
            for (int ks = 0; ks < 4; ++ks) wVd[ks] = *(const f16x8*)(p3 + ks * 32);
        } else {
            #pragma unroll
            for (int ks = 0; ks < 4; ++ks) wVd[ks] = f16x8{};
        }
        #pragma unroll
        for (int q = 0; q < 4; ++q) {
            const _Float16* pi = w16 + W16_eWih + (size_t)(q * 128 + col) * 64 + 8 * g;
            wIh[q][0] = *(const f16x8*)(pi);
            wIh[q][1] = *(const f16x8*)(pi + 32);
            const _Float16* ph = w16 + W16_eWhh + (size_t)(q * 128 + col) * 128 + 8 * g;
            #pragma unroll
            for (int ks = 0; ks < 4; ++ks) wHh[q][ks] = *(const f16x8*)(ph + ks * 32);
        }
    }
    _Float16* hencG = (_Float16*)(ws + OFF_MID);
    __syncthreads();

    float4 xr = make_float4(0.f, 0.f, 0.f, 0.f);  // x_{t+1} prefetch (waves 4-7)

    for (int t = 0; t < TE; ++t) {
        // ---- P1: m1 = [h|c|x] @ [We|Wi]^T  -> av = tanh(m1 + bWi)
        {
            f16x8 aF[10];
            #pragma unroll
            for (int ks = 0; ks < 10; ++ks)
                aF[ks] = *(const f16x8*)&m1In[cc][ks * 32 + 8 * g];
            f32x4 acc = {0.f, 0.f, 0.f, 0.f};
            #pragma unroll
            for (int ks = 0; ks < 8; ++ks)
                acc = mfma16(aF[ks], wWe[ks], acc);
            acc = mfma16(aF[8], wWi[0], acc);
            acc = mfma16(aF[9], wWi[1], acc);
            float bw = bWi[col];
            #pragma unroll
            for (int r = 0; r < 4; ++r)
                avT[4 * g + r][col] = (_Float16)tanh_fast(acc[r] + bw);
        }
        __syncthreads();

        // ---- P2: s = av @ Vd^T (waves 0-3, K=128); waves 4-7 prefetch x_{t+1}
        if (wave < 4) {
            f16x8 aF[4];
            #pragma unroll
            for (int ks = 0; ks < 4; ++ks)
                aF[ks] = *(const f16x8*)&avT[cc][ks * 32 + 8 * g];
            f32x4 acc = {0.f, 0.f, 0.f, 0.f};
            #pragma unroll
            for (int ks = 0; ks < 4; ++ks)
                acc = mfma16(aF[ks], wVd[ks], acc);
            float bv = bVd[col];
            #pragma unroll
            for (int r = 0; r < 4; ++r)
                sS[4 * g + r][col] = acc[r] + bv;
        } else if (t + 1 < TE) {
            int q = tid - 256, m = q >> 4, c4 = (q & 15) * 4;
            xr = *(const float4*)&x_all[((size_t)(b0 + m) * TE + (t + 1)) * F_ + c4];
        }
        __syncthreads();

        // ---- P2b: softmax over 64 + xin = x * softmax(s). row = half-wave
        {
            int m = tid >> 5, c = tid & 31;
            float v0 = sS[m][c], v1 = sS[m][c + 32];
            float mx = fmaxf(v0, v1);
            #pragma unroll
            for (int off = 16; off > 0; off >>= 1) mx = fmaxf(mx, __shfl_xor(mx, off, 64));
            float e0 = fexp2((v0 - mx) * LOG2E);
            float e1 = fexp2((v1 - mx) * LOG2E);
            float sm = e0 + e1;
            #pragma unroll
            for (int off = 16; off > 0; off >>= 1) sm += __shfl_xor(sm, off, 64);
            float rs = frcp(sm);
            encIn[m][c]      = (_Float16)(xf[m][c]      * e0 * rs);
            encIn[m][c + 32] = (_Float16)(xf[m][c + 32] * e1 * rs);
        }
        __syncthreads();

        // ---- P4: enc gates = [xin|h] @ [eWih|eWhh]^T  (K=192; 4 gate-tiles per wave)
        f32x4 ge[4];
        {
            f16x8 aF[6];
            #pragma unroll
            for (int ks = 0; ks < 6; ++ks)
                aF[ks] = *(const f16x8*)&encIn[cc][ks * 32 + 8 * g];
            #pragma unroll
            for (int q = 0; q < 4; ++q) {
                f32x4 acc = {0.f, 0.f, 0.f, 0.f};
                acc = mfma16(aF[0], wIh[q][0], acc);
                acc = mfma16(aF[1], wIh[q][1], acc);
                #pragma unroll
                for (int ks = 0; ks < 4; ++ks)
                    acc = mfma16(aF[2 + ks], wHh[q][ks], acc);
                ge[q] = acc;
            }
        }
        __syncthreads();   // all encIn reads done
        // ---- ep: enc LSTM cell (in-register gates) + h_enc global store + x install
        {
            float bi = bE[col], bf = bE[col + 128], bg = bE[col + 256], bo = bE[col + 384];
            #pragma unroll
            for (int r = 0; r < 4; ++r) {
                int m = 4 * g + r;
                float gi = ge[0][r] + bi, gf = ge[1][r] + bf,
                      gg = ge[2][r] + bg, go = ge[3][r] + bo;
                float cn = sigm(gf) * cE[m][col] + sigm(gi) * tanh_fast(gg);
                float h  = sigm(go) * tanh_fast(cn);
                cE[m][col] = cn;
                _Float16 hh = (_Float16)h;
                encIn[m][64 + col] = hh;
                m1In[m][col]       = hh;
                m1In[m][128 + col] = (_Float16)cn;
                hencG[((size_t)(b0 + m) * TE + t) * H_ + col] = hh;
            }
            if (tid >= 256 && t + 1 < TE) {
                int q = tid - 256, m = q >> 4, c4 = (q & 15) * 4;
                *(float4*)&xf[m][c4] = xr;
                m1In[m][256 + c4]     = (_Float16)xr.x;
                m1In[m][256 + c4 + 1] = (_Float16)xr.y;
                m1In[m][256 + c4 + 2] = (_Float16)xr.z;
                m1In[m][256 + c4 + 3] = (_Float16)xr.w;
            }
        }
        __syncthreads();
    }
}

// ---------------- mid LSTM: 64 blocks x 512 thr, 16 rows/block (unchanged) ----------------
__global__ __launch_bounds__(512, 1) void mid_kernel(
    const float* __restrict__ Wx_b,
    float* __restrict__ ws)
{
    __shared__ __align__(16) _Float16 midIn[16][264];  // [h_enc(0:128)|h_mid(128:256)]
    __shared__ __align__(16) float cM[16][132];        // mid c fp32 master
    __shared__ float bM[G_], bWx[H_];

    const int tid  = threadIdx.x;
    const int wave = tid >> 6;
    const int lane = tid & 63;
    const int g    = lane >> 4;
    const int cc   = lane & 15;
    const int b0   = blockIdx.x * 16;
    const int col  = wave * 16 + cc;

    for (int i = tid; i < 16 * 264; i += 512) ((_Float16*)midIn)[i] = (_Float16)0.f;
    for (int i = tid; i < 16 * 132; i += 512) ((float*)cM)[i] = 0.f;
    if (tid < H_) bWx[tid] = Wx_b[tid];
    bM[tid] = ws[OFF_MIDB + tid];

    // ---- persistent per-wave B-fragments ----
    const _Float16* w16 = (const _Float16*)(ws + OFF_W16);
    f16x8 wIhB[4][4], wHhB[4][4], wWx[4];
    {
        #pragma unroll
        for (int q = 0; q < 4; ++q) {
            const _Float16* pi = w16 + W16_mWih + (size_t)(q * 128 + col) * 128 + 8 * g;
            const _Float16* ph = w16 + W16_mWhh + (size_t)(q * 128 + col) * 128 + 8 * g;
            #pragma unroll
            for (int ks = 0; ks < 4; ++ks) {
                wIhB[q][ks] = *(const f16x8*)(pi + ks * 32);
                wHhB[q][ks] = *(const f16x8*)(ph + ks * 32);
            }
        }
        const _Float16* px = w16 + W16_Wx + (size_t)col * 128 + 8 * g;
        #pragma unroll
        for (int ks = 0; ks < 4; ++ks) wWx[ks] = *(const f16x8*)(px + ks * 32);
    }

    _Float16* hencG = (_Float16*)(ws + OFF_MID);   // h_enc in, midH out (in-place)
    _Float16* wxH   = (_Float16*)(ws + OFF_WX);
    __syncthreads();

    // install h_enc(0)
    if (tid < 256) {
        int m = tid >> 4, s8 = (tid & 15) * 8;
        *(f16x8*)&midIn[m][s8] = *(const f16x8*)&hencG[((size_t)(b0 + m) * TE + 0) * H_ + s8];
    }
    __syncthreads();

    f16x8 hpre = {};
    f32x4 accx = {0.f, 0.f, 0.f, 0.f};

    for (int t = 0; t < TE; ++t) {
        // ---- P6: mid gates = [h_enc(t)|h_mid(t-1)] @ [mWih|mWhh]^T (K=256) + wx(t-1)
        f32x4 gm[4];
        {
            f16x8 aF[8];
            #pragma unroll
            for (int ks = 0; ks < 8; ++ks)
                aF[ks] = *(const f16x8*)&midIn[cc][ks * 32 + 8 * g];
            #pragma unroll
            for (int q = 0; q < 4; ++q) {
                f32x4 acc = {0.f, 0.f, 0.f, 0.f};
                #pragma unroll
                for (int ks = 0; ks < 4; ++ks)
                    acc = mfma16(aF[ks], wIhB[q][ks], acc);
                #pragma unroll
                for (int ks = 0; ks < 4; ++ks)
                    acc = mfma16(aF[4 + ks], wHhB[q][ks], acc);
                gm[q] = acc;
            }
            if (t > 0) {   // wx(t-1) = h_mid(t-1) @ Wx^T (aF[4..7] already hold h_mid(t-1))
                f32x4 acc = {0.f, 0.f, 0.f, 0.f};
                #pragma unroll
                for (int ks = 0; ks < 4; ++ks)
                    acc = mfma16(aF[4 + ks], wWx[ks], acc);
                accx = acc;
            }
        }
        if (tid < 256 && t + 1 < TE) {   // prefetch h_enc(t+1)
            int m = tid >> 4, s8 = (tid & 15) * 8;
            hpre = *(const f16x8*)&hencG[((size_t)(b0 + m) * TE + (t + 1)) * H_ + s8];
        }
        __syncthreads();

        // ---- ep: mid LSTM cell + midH store (in-place) + wx(t-1) store + h_enc(t+1) install
        {
            float bi = bM[col], bf = bM[col + 128], bg = bM[col + 256], bo = bM[col + 384];
            float bw = bWx[col];
            #pragma unroll
            for (int r = 0; r < 4; ++r) {
                int m = 4 * g + r;
                float gi = gm[0][r] + bi, gf = gm[1][r] + bf,
                      gg = gm[2][r] + bg, go = gm[3][r] + bo;
                float cn = sigm(gf) * cM[m][col] + sigm(gi) * tanh_fast(gg);
                float h  = sigm(go) * tanh_fast(cn);
                cM[m][col] = cn;
                _Float16 hh = (_Float16)h;
                midIn[m][128 + col] = hh;
                hencG[((size_t)(b0 + m) * TE + t) * H_ + col] = hh;   // midH(t)
                if (t > 0)
                    wxH[((size_t)(b0 + m) * TE + (t - 1)) * H_ + col] = (_Float16)(accx[r] + bw);
            }
            if (tid < 256 && t + 1 < TE) {
                int m = tid >> 4, s8 = (tid & 15) * 8;
                *(f16x8*)&midIn[m][s8] = hpre;
            }
        }
        __syncthreads();
    }

    // final wx(TE-1)
    {
        f16x8 ax[4];
        #pragma unroll
        for (int ks = 0; ks < 4; ++ks)
            ax[ks] = *(const f16x8*)&midIn[cc][128 + ks * 32 + 8 * g];
        f32x4 acc = {0.f, 0.f, 0.f, 0.f};
        #pragma unroll
        for (int ks = 0; ks < 4; ++ks)
            acc = mfma16(ax[ks], wWx[ks], acc);
        float bw = bWx[col];
        #pragma unroll
        for (int r = 0; r < 4; ++r) {
            int m = 4 * g + r;
            wxH[((size_t)(b0 + m) * TE + (TE - 1)) * H_ + col] = (_Float16)(acc[r] + bw);
        }
    }
    // final states for decoder
    for (int idx = tid; idx < 2048; idx += 512) {
        int m = idx >> 7, j = idx & 127;
        ws[OFF_STH + (b0 + m) * H_ + j] = (float)midIn[m][128 + j];
        ws[OFF_STC + (b0 + m) * H_ + j] = cM[m][j];
    }
}

// ---------------- decoder v5: 512 blocks x 512 thr, 2 rows/block, MFMA P1/P4, balanced P2/P3 ----------------
__global__ __launch_bounds__(512, 2) void dec_kernel(
    const float* __restrict__ Vw_in,
    const float* __restrict__ Vb_in,
    const float* __restrict__ rw_in,
    const float* __restrict__ rb_in,
    const float* __restrict__ ws,
    float* __restrict__ out)
{
    __shared__ __align__(16) _Float16 hcA[16][264];    // A for P1: [h|c] rows 0-1, rows 2-15 zero
    __shared__ __align__(16) _Float16 dinA[16][264];   // A for P4: [din|h] rows 0-1, rows 2-15 zero
    __shared__ __align__(16) float qv[2][132];         // q fp32
    __shared__ __align__(16) float sv[2][TE];          // scores
    __shared__ __align__(16) float dpart[16][2][H_];   // P3 partials (16 slices)
    __shared__ __align__(16) float ggs[2][G_];         // gates
    __shared__ __align__(16) float cD[2][H_];          // c fp32 master
    __shared__ __align__(16) float hFl[2][H_];         // h fp32 (output dot)
    __shared__ float bDL[G_], VwL[H_], rwL[H_];

    const int tid  = threadIdx.x;
    const int wave = tid >> 6;
    const int lane = tid & 63;
    const int g    = lane >> 4;
    const int cc   = lane & 15;
    const int b0   = blockIdx.x * 2;
    const float Vb = Vb_in[0], rb = rb_in[0];

    for (int i = tid; i < 16 * 264; i += 512) {
        ((_Float16*)hcA)[i]  = (_Float16)0.f;
        ((_Float16*)dinA)[i] = (_Float16)0.f;
    }
    bDL[tid] = ws[OFF_DECB + tid];
    if (tid < H_) { VwL[tid] = Vw_in[tid]; rwL[tid] = rw_in[tid]; }
    __syncthreads();
    if (tid < 256) {
        int r = tid >> 7, j = tid & 127;
        float sh = ws[OFF_STH + (size_t)(b0 + r) * H_ + j];
        float sc = ws[OFF_STC + (size_t)(b0 + r) * H_ + j];
        hcA[r][j]        = (_Float16)sh;
        hcA[r][128 + j]  = (_Float16)sc;
        dinA[r][128 + j] = (_Float16)sh;
        cD[r][j] = sc;
    }
    __syncthreads();

    const _Float16* WhP  = (const _Float16*)(ws + OFF_WhT);
    const _Float16* dWP  = (const _Float16*)(ws + OFF_dWihT);
    const _Float16* wxG  = (const _Float16*)(ws + OFF_WX);
    const _Float16* midG = (const _Float16*)(ws + OFF_MID);

    for (int td = 0; td < TD; ++td) {
        // ---- P1: q[2][128] = [h|c] @ Wh^T via MFMA (M=2-in-16). wave = 16-col tile, K=256
        {
            f16x8 aF[8];
            #pragma unroll
            for (int ks = 0; ks < 8; ++ks)
                aF[ks] = *(const f16x8*)&hcA[cc][ks * 32 + 8 * g];
            f32x4 acc = {0.f, 0.f, 0.f, 0.f};
            #pragma unroll
            for (int ks = 0; ks < 8; ++ks) {
                f16x8 wb = *(const f16x8*)(WhP + (((size_t)(wave * 8 + ks) * 64 + lane) * 8));
                acc = mfma16(aF[ks], wb, acc);
            }
            if (g == 0) {
                qv[0][wave * 16 + cc] = acc[0];
                qv[1][wave * 16 + cc] = acc[1];
            }
        }
        __syncthreads();

        // ---- P2: scores. 1344 tasks = (r, tp, quarter-32); 4-lane shuffle reduce.
        // Rounds: 512 + 512 + 320 (wave-aligned tail).
        for (int task = tid; task < 8 * TE; task += 512) {
            int q4 = task & 3, rt = task >> 2;
            int r  = (rt >= TE) ? 1 : 0;
            int tp = rt - r * TE;
            const _Float16* wxp = wxG + ((size_t)(b0 + r) * TE + tp) * H_ + q4 * 32;
            const float* qp = &qv[r][q4 * 32];
            const float* vp = &VwL[q4 * 32];
            float acc = 0.f;
            #pragma unroll
            for (int k8 = 0; k8 < 4; ++k8) {
                f16x8 wv = *(const f16x8*)(wxp + k8 * 8);
                int j = k8 * 8;
                float4 q0 = *(const float4*)(qp + j), q1 = *(const float4*)(qp + j + 4);
                float4 v0 = *(const float4*)(vp + j), v1 = *(const float4*)(vp + j + 4);
                acc += tanh_fast(q0.x + (float)wv[0]) * v0.x + tanh_fast(q0.y + (float)wv[1]) * v0.y
                     + tanh_fast(q0.z + (float)wv[2]) * v0.z + tanh_fast(q0.w + (float)wv[3]) * v0.w;
                acc += tanh_fast(q1.x + (float)wv[4]) * v1.x + tanh_fast(q1.y + (float)wv[5]) * v1.y
                     + tanh_fast(q1.z + (float)wv[6]) * v1.z + tanh_fast(q1.w + (float)wv[7]) * v1.w;
            }
            acc += __shfl_xor(acc, 1, 64);
            acc += __shfl_xor(acc, 2, 64);
            if (q4 == 0) sv[r][tp] = acc + Vb;
        }
        __syncthreads();

        // ---- P3: dec_in partials. 512 thr = 16 slices x (2 r x 16 j8); ~10.5 tp each
        {
            int sl = tid >> 5, rem = tid & 31, r = rem >> 4, j8 = rem & 15;
            int t0 = (sl * TE) >> 4, t1 = ((sl + 1) * TE) >> 4;
            const _Float16* mp = midG + (size_t)(b0 + r) * TE * H_ + j8 * 8;
            float a0 = 0.f, a1 = 0.f, a2 = 0.f, a3 = 0.f, a4 = 0.f, a5 = 0.f, a6 = 0.f, a7 = 0.f;
            for (int tp = t0; tp < t1; ++tp) {
                float s = sv[r][tp];
                f16x8 mv = *(const f16x8*)(mp + (size_t)tp * H_);
                a0 = __builtin_fmaf(s, (float)mv[0], a0);
                a1 = __builtin_fmaf(s, (float)mv[1], a1);
                a2 = __builtin_fmaf(s, (float)mv[2], a2);
                a3 = __builtin_fmaf(s, (float)mv[3], a3);
                a4 = __builtin_fmaf(s, (float)mv[4], a4);
                a5 = __builtin_fmaf(s, (float)mv[5], a5);
                a6 = __builtin_fmaf(s, (float)mv[6], a6);
                a7 = __builtin_fmaf(s, (float)mv[7], a7);
            }
            float* dp = &dpart[sl][r][j8 * 8];
            dp[0] = a0; dp[1] = a1; dp[2] = a2; dp[3] = a3;
            dp[4] = a4; dp[5] = a5; dp[6] = a6; dp[7] = a7;
        }
        __syncthreads();
        // ---- P3b: combine 16 -> dinA fp16
        if (tid < 256) {
            int r = tid >> 7, j = tid & 127;
            float d = 0.f;
            #pragma unroll
            for (int sl = 0; sl < 16; ++sl) d += dpart[sl][r][j];
            dinA[r][j] = (_Float16)d;
        }
        __syncthreads();

        // ---- P4: gates[2][512] = [din|h] @ [dWih|dWhh]^T via MFMA. 4 n-tiles/wave, K=256
        {
            f16x8 aF[8];
            #pragma unroll
            for (int ks = 0; ks < 8; ++ks)
                aF[ks] = *(const f16x8*)&dinA[cc][ks * 32 + 8 * g];
            #pragma unroll
            for (int q = 0; q < 4; ++q) {
                int nt = wave * 4 + q;
                f32x4 acc = {0.f, 0.f, 0.f, 0.f};
                #pragma unroll
                for (int ks = 0; ks < 8; ++ks) {
                    f16x8 wb = *(const f16x8*)(dWP + (((size_t)(nt * 8 + ks) * 64 + lane) * 8));
                    acc = mfma16(aF[ks], wb, acc);
                }
                if (g == 0) {
                    ggs[0][nt * 16 + cc] = acc[0];
                    ggs[1][nt * 16 + cc] = acc[1];
                }
            }
        }
        __syncthreads();

        // ---- P5: LSTM cell
        if (tid < 256) {
            int r = tid >> 7, j = tid & 127;
            float gi = ggs[r][j]       + bDL[j];
            float gf = ggs[r][j + 128] + bDL[j + 128];
            float gg = ggs[r][j + 256] + bDL[j + 256];
            float go = ggs[r][j + 384] + bDL[j + 384];
            float cn = sigm(gf) * cD[r][j] + sigm(gi) * tanh_fast(gg);
            float h  = sigm(go) * tanh_fast(cn);
            cD[r][j]  = cn;
            hFl[r][j] = h;
            hcA[r][j]        = (_Float16)h;
            hcA[r][128 + j]  = (_Float16)cn;
            dinA[r][128 + j] = (_Float16)h;
        }
        __syncthreads();

        // ---- P6: output dot (waves 0-1; overlaps next P1, no barrier needed)
        if (tid < 128) {
            int r = tid >> 6, l = tid & 63;
            float v = hFl[r][l] * rwL[l] + hFl[r][l + 64] * rwL[l + 64];
            #pragma unroll
            for (int off = 32; off > 0; off >>= 1) v += __shfl_xor(v, off, 64);
            if (l == 0) out[(size_t)(b0 + r) * TD + td] = v + rb;
        }
    }
}

extern "C" void kernel_launch(void* const* d_in, const int* in_sizes, int n_in,
                              void* d_out, int out_size, void* d_ws, size_t ws_size,
                              hipStream_t stream)
{
    (void)in_sizes; (void)n_in; (void)out_size;
    if (ws_size < (size_t)WS_FLOATS * sizeof(float)) return;

    const float* x_all = (const float*)d_in[0];
    const float* Wi_b  = (const float*)d_in[3];
    const float* Vd_b  = (const float*)d_in[6];
    const float* Wx_b  = (const float*)d_in[16];
    const float* V_w   = (const float*)d_in[18];
    const float* V_b   = (const float*)d_in[19];
    const float* reg_w = (const float*)d_in[24];
    const float* reg_b = (const float*)d_in[25];
    float* ws  = (float*)d_ws;
    float* out = (float*)d_out;

    PrepArgs pa{
        (const float*)d_in[4],  // We_w
        (const float*)d_in[2],  // Wi_w
        (const float*)d_in[5],  // Vd_w
        (const float*)d_in[7],  // enc_Wih
        (const float*)d_in[8],  // enc_Whh
        (const float*)d_in[9],  // enc_bih
        (const float*)d_in[10], // enc_bhh
        (const float*)d_in[11], // mid_Wih
        (const float*)d_in[12], // mid_Whh
        (const float*)d_in[13], // mid_bih
        (const float*)d_in[14], // mid_bhh
        (const float*)d_in[15], // Wx_w
        (const float*)d_in[17], // Wh_w
        (const float*)d_in[20], // dec_Wih
        (const float*)d_in[21], // dec_Whh
        (const float*)d_in[22], // dec_bih
        (const float*)d_in[23]  // dec_bhh
    };

    prep_kernel<<<56, 256, 0, stream>>>(pa, ws);
    enc_kernel<<<64, 512, 0, stream>>>(x_all, Wi_b, Vd_b, ws);
    mid_kernel<<<64, 512, 0, stream>>>(Wx_b, ws);
    dec_kernel<<<512, 512, 0, stream>>>(V_w, V_b, reg_w, reg_b, ws, out);
}